// Round 1
// baseline (208.987 us; speedup 1.0000x reference)
//
#include <hip/hip_runtime.h>
#include <cstdint>
#include <cstddef>

#define BATCH 32
#define CLEN  1024
#define QLEN  128
#define HID   256

// ---------------- rowdot: out[row] = dot(X[row, :256], w) ----------------
__global__ __launch_bounds__(256) void rowdot_kernel(
    const float* __restrict__ X, const float* __restrict__ w,
    float* __restrict__ out, int nrows)
{
    int row  = blockIdx.x * 4 + (threadIdx.x >> 6);
    int lane = threadIdx.x & 63;
    if (row >= nrows) return;
    float4 x  = *reinterpret_cast<const float4*>(X + (size_t)row * HID + lane * 4);
    float4 wv = *reinterpret_cast<const float4*>(w + lane * 4);
    float d = x.x * wv.x + x.y * wv.y + x.z * wv.z + x.w * wv.w;
    #pragma unroll
    for (int off = 32; off; off >>= 1) d += __shfl_down(d, off, 64);
    if (lane == 0) out[row] = d;
}

// ---------------- S = cdot + qdot + (ctx*cqw)@query^T + bias ----------------
// Also computes row (axis=2) softmax stats: rowmax, 1/rowsum.
// Block: 256 threads, tile 64c x 128q, K=H=256 in chunks of 64.
__global__ __launch_bounds__(256) void s_kernel(
    const float* __restrict__ context, const float* __restrict__ query,
    const float* __restrict__ cqw, const float* __restrict__ cdot,
    const float* __restrict__ qdot, const float* __restrict__ bias,
    float* __restrict__ S, float* __restrict__ rowmax, float* __restrict__ rowsumr)
{
    __shared__ float mcT[64 * 68];   // [hh][r]  (r=0..63)
    __shared__ float qS[64 * 132];   // [hh][q]  (q=0..127)
    int b  = blockIdx.x >> 4;
    int c0 = (blockIdx.x & 15) * 64;
    int t  = threadIdx.x;
    int qg = t & 31;      // q group: q = qg*4 + j
    int rg = t >> 5;      // row group: r = rg*8 + i
    float acc[8][4];
    #pragma unroll
    for (int i = 0; i < 8; i++)
        #pragma unroll
        for (int j = 0; j < 4; j++) acc[i][j] = 0.f;

    const float* ctxB = context + ((size_t)b * CLEN + c0) * HID;
    const float* qryB = query + (size_t)b * QLEN * HID;

    for (int h0 = 0; h0 < HID; h0 += 64) {
        for (int i = 0; i < 16; i++) {
            int e = t + 256 * i;
            int hh = e & 63, r = e >> 6;
            mcT[hh * 68 + r] = ctxB[(size_t)r * HID + h0 + hh] * cqw[h0 + hh];
        }
        for (int i = 0; i < 32; i++) {
            int e = t + 256 * i;
            int hh = e & 63, q = e >> 6;
            qS[hh * 132 + q] = qryB[(size_t)q * HID + h0 + hh];
        }
        __syncthreads();
        for (int hh = 0; hh < 64; hh++) {
            float4 qv = *reinterpret_cast<const float4*>(&qS[hh * 132 + qg * 4]);
            float4 m0 = *reinterpret_cast<const float4*>(&mcT[hh * 68 + rg * 8]);
            float4 m1 = *reinterpret_cast<const float4*>(&mcT[hh * 68 + rg * 8 + 4]);
            float qa[4] = {qv.x, qv.y, qv.z, qv.w};
            float ma[8] = {m0.x, m0.y, m0.z, m0.w, m1.x, m1.y, m1.z, m1.w};
            #pragma unroll
            for (int i = 0; i < 8; i++)
                #pragma unroll
                for (int j = 0; j < 4; j++) acc[i][j] += ma[i] * qa[j];
        }
        __syncthreads();
    }

    float cd[8];
    #pragma unroll
    for (int i = 0; i < 8; i++) cd[i] = cdot[(size_t)b * CLEN + c0 + rg * 8 + i];
    float4 qd4 = *reinterpret_cast<const float4*>(&qdot[(size_t)b * QLEN + qg * 4]);
    float qd[4] = {qd4.x, qd4.y, qd4.z, qd4.w};
    float bv = bias[0];
    float* Sb = S + ((size_t)b * CLEN + c0) * QLEN;

    #pragma unroll
    for (int i = 0; i < 8; i++) {
        float4 sv;
        sv.x = acc[i][0] + cd[i] + qd[0] + bv;
        sv.y = acc[i][1] + cd[i] + qd[1] + bv;
        sv.z = acc[i][2] + cd[i] + qd[2] + bv;
        sv.w = acc[i][3] + cd[i] + qd[3] + bv;
        *reinterpret_cast<float4*>(&Sb[(size_t)(rg * 8 + i) * QLEN + qg * 4]) = sv;
        // row softmax stats over 128 q spread across 32 lanes (4 per lane)
        float m = fmaxf(fmaxf(sv.x, sv.y), fmaxf(sv.z, sv.w));
        #pragma unroll
        for (int off = 16; off; off >>= 1) m = fmaxf(m, __shfl_xor(m, off, 64));
        float s = __expf(sv.x - m) + __expf(sv.y - m) + __expf(sv.z - m) + __expf(sv.w - m);
        #pragma unroll
        for (int off = 16; off; off >>= 1) s += __shfl_xor(s, off, 64);
        if (qg == 0) {
            rowmax[(size_t)b * CLEN + c0 + rg * 8 + i] = m;
            rowsumr[(size_t)b * CLEN + c0 + rg * 8 + i] = 1.0f / s;
        }
    }
}

// ---------------- column (axis=1) softmax stats: partials over c-chunks ----------------
__global__ __launch_bounds__(256) void colstats1_kernel(
    const float* __restrict__ S, float* __restrict__ pmax, float* __restrict__ psum)
{
    int b = blockIdx.x, chunk = blockIdx.y;
    int t = threadIdx.x;
    int q = t & 127, half = t >> 7;
    const float* Sb = S + ((size_t)b * CLEN + chunk * 128) * QLEN;
    float m = -1e30f, s = 0.f;
    for (int k = 0; k < 64; k++) {
        int c = half + 2 * k;
        float v = Sb[(size_t)c * QLEN + q];
        float nm = fmaxf(m, v);
        s = s * __expf(m - nm) + __expf(v - nm);
        m = nm;
    }
    __shared__ float sm[256], ss[256];
    sm[t] = m; ss[t] = s;
    __syncthreads();
    if (t < 128) {
        float m2 = sm[t + 128], s2 = ss[t + 128];
        float M = fmaxf(m, m2);
        float Sv = s * __expf(m - M) + s2 * __expf(m2 - M);
        pmax[((size_t)b * 8 + chunk) * QLEN + q] = M;
        psum[((size_t)b * 8 + chunk) * QLEN + q] = Sv;
    }
}

__global__ __launch_bounds__(256) void colstats2_kernel(
    const float* __restrict__ pmax, const float* __restrict__ psum,
    float* __restrict__ colmax, float* __restrict__ colsumr)
{
    int gid = blockIdx.x * 256 + threadIdx.x;   // 0..4095 = b*128+q
    int b = gid >> 7, q = gid & 127;
    float m = -1e30f, s = 0.f;
    for (int ch = 0; ch < 8; ch++) {
        float m2 = pmax[((size_t)b * 8 + ch) * QLEN + q];
        float s2 = psum[((size_t)b * 8 + ch) * QLEN + q];
        float M = fmaxf(m, m2);
        s = s * __expf(m - M) + s2 * __expf(m2 - M);
        m = M;
    }
    colmax[gid] = m;
    colsumr[gid] = 1.0f / s;
}

// ---------------- T[q,h] = sum_c softmax_row(S)[c,q] * ctx[c,h]  (K-split x4) ----------------
__global__ __launch_bounds__(256) void t_kernel(
    const float* __restrict__ S, const float* __restrict__ context,
    const float* __restrict__ rowmax, const float* __restrict__ rowsumr,
    float* __restrict__ Tpart)
{
    __shared__ float sbbT[64 * 132];  // [cc][q]
    __shared__ float ctxS[64 * 68];   // [cc][hh]
    int b  = blockIdx.y;
    int hc = blockIdx.x >> 2, cs = blockIdx.x & 3;
    int h0 = hc * 64;
    int t  = threadIdx.x;
    int hg = t & 15;    // h = h0 + hg*4 + j
    int qg = t >> 4;    // q = qg*8 + i
    float acc[8][4];
    #pragma unroll
    for (int i = 0; i < 8; i++)
        #pragma unroll
        for (int j = 0; j < 4; j++) acc[i][j] = 0.f;

    for (int c0 = cs * 256; c0 < cs * 256 + 256; c0 += 64) {
        for (int i = 0; i < 32; i++) {
            int e = t + 256 * i;
            int cc = e >> 7, q = e & 127;
            int c = c0 + cc;
            float v  = S[((size_t)b * CLEN + c) * QLEN + q];
            float rm = rowmax[(size_t)b * CLEN + c];
            float rr = rowsumr[(size_t)b * CLEN + c];
            sbbT[cc * 132 + q] = __expf(v - rm) * rr;
        }
        for (int i = 0; i < 16; i++) {
            int e = t + 256 * i;
            int cc = e >> 6, hh = e & 63;
            ctxS[cc * 68 + hh] = context[((size_t)b * CLEN + c0 + cc) * HID + h0 + hh];
        }
        __syncthreads();
        for (int cc = 0; cc < 64; cc++) {
            float4 s0 = *reinterpret_cast<const float4*>(&sbbT[cc * 132 + qg * 8]);
            float4 s1 = *reinterpret_cast<const float4*>(&sbbT[cc * 132 + qg * 8 + 4]);
            float4 cv = *reinterpret_cast<const float4*>(&ctxS[cc * 68 + hg * 4]);
            float sa[8] = {s0.x, s0.y, s0.z, s0.w, s1.x, s1.y, s1.z, s1.w};
            float ca[4] = {cv.x, cv.y, cv.z, cv.w};
            #pragma unroll
            for (int i = 0; i < 8; i++)
                #pragma unroll
                for (int j = 0; j < 4; j++) acc[i][j] += sa[i] * ca[j];
        }
        __syncthreads();
    }
    float* Tp = Tpart + ((size_t)cs * BATCH + b) * QLEN * HID;
    #pragma unroll
    for (int i = 0; i < 8; i++) {
        float4 v = make_float4(acc[i][0], acc[i][1], acc[i][2], acc[i][3]);
        *reinterpret_cast<float4*>(&Tp[(size_t)(qg * 8 + i) * HID + h0 + hg * 4]) = v;
    }
}

__global__ __launch_bounds__(256) void t_reduce_kernel(
    const float* __restrict__ Tpart, float* __restrict__ T)
{
    int idx = blockIdx.x * 256 + threadIdx.x;   // float4 index, 262144 total
    const float4* p = reinterpret_cast<const float4*>(Tpart);
    float4 a = p[idx];
    float4 b = p[idx + 262144];
    float4 c = p[idx + 524288];
    float4 d = p[idx + 786432];
    float4 r = make_float4(a.x + b.x + c.x + d.x, a.y + b.y + c.y + d.y,
                           a.z + b.z + c.z + d.z, a.w + b.w + c.w + d.w);
    reinterpret_cast<float4*>(T)[idx] = r;
}

// ---------------- A = S@query, B = softmax_col(S)@T, write concat output ----------------
// Block: 256 threads, tile 64c x 64h, K=q=128 in chunks of 32.
__global__ __launch_bounds__(256) void ab_out_kernel(
    const float* __restrict__ S, const float* __restrict__ query,
    const float* __restrict__ T, const float* __restrict__ context,
    const float* __restrict__ colmax, const float* __restrict__ colsumr,
    float* __restrict__ out)
{
    __shared__ float sT[32 * 68];   // [qq][c]   raw S transposed
    __shared__ float sbT[32 * 68];  // [qq][c]   col-softmaxed S transposed
    __shared__ float qSh[32 * 68];  // [qq][hh]
    __shared__ float tSh[32 * 68];  // [qq][hh]
    int b  = blockIdx.y;
    int ct = blockIdx.x >> 2, ht = blockIdx.x & 3;
    int c0 = ct * 64, h0 = ht * 64;
    int t  = threadIdx.x;
    int hg = t & 15;   // h = h0 + hg*4 + j
    int cg = t >> 4;   // c = c0 + cg*4 + i
    float accA[4][4], accB[4][4];
    #pragma unroll
    for (int i = 0; i < 4; i++)
        #pragma unroll
        for (int j = 0; j < 4; j++) { accA[i][j] = 0.f; accB[i][j] = 0.f; }

    for (int q0 = 0; q0 < QLEN; q0 += 32) {
        for (int i = 0; i < 8; i++) {
            int e = t + 256 * i;
            int qq = e & 31, cid = e >> 5;
            float v  = S[((size_t)b * CLEN + c0 + cid) * QLEN + q0 + qq];
            float cm = colmax[(size_t)b * QLEN + q0 + qq];
            float cr = colsumr[(size_t)b * QLEN + q0 + qq];
            sT[qq * 68 + cid]  = v;
            sbT[qq * 68 + cid] = __expf(v - cm) * cr;
        }
        for (int i = 0; i < 8; i++) {
            int e = t + 256 * i;
            int qq = e >> 6, hh = e & 63;
            qSh[qq * 68 + hh] = query[((size_t)b * QLEN + q0 + qq) * HID + h0 + hh];
            tSh[qq * 68 + hh] = T[((size_t)b * QLEN + q0 + qq) * HID + h0 + hh];
        }
        __syncthreads();
        for (int qq = 0; qq < 32; qq++) {
            float4 sa4 = *reinterpret_cast<const float4*>(&sT[qq * 68 + cg * 4]);
            float4 sb4 = *reinterpret_cast<const float4*>(&sbT[qq * 68 + cg * 4]);
            float4 qv4 = *reinterpret_cast<const float4*>(&qSh[qq * 68 + hg * 4]);
            float4 tv4 = *reinterpret_cast<const float4*>(&tSh[qq * 68 + hg * 4]);
            float sa[4] = {sa4.x, sa4.y, sa4.z, sa4.w};
            float sb[4] = {sb4.x, sb4.y, sb4.z, sb4.w};
            float qa[4] = {qv4.x, qv4.y, qv4.z, qv4.w};
            float ta[4] = {tv4.x, tv4.y, tv4.z, tv4.w};
            #pragma unroll
            for (int i = 0; i < 4; i++)
                #pragma unroll
                for (int j = 0; j < 4; j++) {
                    accA[i][j] += sa[i] * qa[j];
                    accB[i][j] += sb[i] * ta[j];
                }
        }
        __syncthreads();
    }

    #pragma unroll
    for (int i = 0; i < 4; i++) {
        int c = c0 + cg * 4 + i;
        float4 cv = *reinterpret_cast<const float4*>(
            &context[((size_t)b * CLEN + c) * HID + h0 + hg * 4]);
        size_t o = ((size_t)b * CLEN + c) * (4 * HID) + h0 + hg * 4;
        float4 av = make_float4(accA[i][0], accA[i][1], accA[i][2], accA[i][3]);
        float4 bv = make_float4(accB[i][0], accB[i][1], accB[i][2], accB[i][3]);
        *reinterpret_cast<float4*>(&out[o])       = cv;
        *reinterpret_cast<float4*>(&out[o + 256]) = av;
        *reinterpret_cast<float4*>(&out[o + 512]) =
            make_float4(cv.x * av.x, cv.y * av.y, cv.z * av.z, cv.w * av.w);
        *reinterpret_cast<float4*>(&out[o + 768]) =
            make_float4(cv.x * bv.x, cv.y * bv.y, cv.z * bv.z, cv.w * bv.w);
    }
}

extern "C" void kernel_launch(void* const* d_in, const int* in_sizes, int n_in,
                              void* d_out, int out_size, void* d_ws, size_t ws_size,
                              hipStream_t stream)
{
    (void)in_sizes; (void)n_in; (void)out_size; (void)ws_size;
    const float* context  = (const float*)d_in[0];
    const float* query    = (const float*)d_in[1];
    // d_in[2], d_in[3]: masks (all false, unused by reference math)
    const float* c_weight  = (const float*)d_in[4];
    const float* q_weight  = (const float*)d_in[5];
    const float* cq_weight = (const float*)d_in[6];
    const float* bias      = (const float*)d_in[7];
    float* out = (float*)d_out;
    float* ws  = (float*)d_ws;

    float* S       = ws;                          // 4194304
    float* cdot    = S + 4194304;                 // 32768
    float* qdot    = cdot + 32768;                // 4096
    float* rowmax  = qdot + 4096;                 // 32768
    float* rowsumr = rowmax + 32768;              // 32768
    float* pmax    = rowsumr + 32768;             // 32768
    float* psum    = pmax + 32768;                // 32768
    float* colmax  = psum + 32768;                // 4096
    float* colsumr = colmax + 4096;               // 4096
    float* Tpart   = colsumr + 4096;              // 4 * 1048576
    float* T       = Tpart + 4194304;             // 1048576

    rowdot_kernel<<<8192, 256, 0, stream>>>(context, c_weight, cdot, BATCH * CLEN);
    rowdot_kernel<<<1024, 256, 0, stream>>>(query, q_weight, qdot, BATCH * QLEN);
    s_kernel<<<BATCH * 16, 256, 0, stream>>>(context, query, cq_weight, cdot, qdot,
                                             bias, S, rowmax, rowsumr);
    colstats1_kernel<<<dim3(BATCH, 8), 256, 0, stream>>>(S, pmax, psum);
    colstats2_kernel<<<16, 256, 0, stream>>>(pmax, psum, colmax, colsumr);
    t_kernel<<<dim3(16, BATCH), 256, 0, stream>>>(S, context, rowmax, rowsumr, Tpart);
    t_reduce_kernel<<<1024, 256, 0, stream>>>(Tpart, T);
    ab_out_kernel<<<dim3(64, BATCH), 256, 0, stream>>>(S, query, T, context,
                                                       colmax, colsumr, out);
}

// Round 2
// 119.068 us; speedup vs baseline: 1.7552x; 1.7552x over previous
//
#include <hip/hip_runtime.h>
#include <cstdint>
#include <cstddef>

#define BATCH 32
#define CLEN  1024
#define QLEN  128
#define HID   256

typedef __attribute__((ext_vector_type(8))) short bf16x8;
typedef __attribute__((ext_vector_type(4))) float f32x4;

#define MFMA(a, b, c) __builtin_amdgcn_mfma_f32_16x16x32_bf16((a), (b), (c), 0, 0, 0)

__device__ __forceinline__ ushort f2b(float f) {
    union { float f; uint u; } v; v.f = f;
    uint r = (v.u + 0x7fffu + ((v.u >> 16) & 1u)) >> 16;
    return (ushort)r;
}
__device__ __forceinline__ float b2f(ushort u) {
    union { uint u; float f; } v; v.u = ((uint)u) << 16;
    return v.f;
}

// ================= prep_ctx: ctxT[b][h][c] bf16, cdot[b][c] =================
// grid 512 (b*16 + ctile64), 256 thr
__global__ __launch_bounds__(256) void prep_ctx_kernel(
    const float* __restrict__ context, const float* __restrict__ cw,
    ushort* __restrict__ ctxT, float* __restrict__ cdot)
{
    __shared__ ushort lds[64][258];
    int bid = blockIdx.x;
    int b = bid >> 4, c0 = (bid & 15) * 64;
    int t = threadIdx.x;
    int r = t >> 2, qd = t & 3;
    const float* src = context + ((size_t)(b * CLEN + c0 + r)) * HID;
    float dot = 0.f;
    #pragma unroll
    for (int j = 0; j < 16; j++) {
        int h = j * 16 + qd * 4;
        float4 v = *reinterpret_cast<const float4*>(src + h);
        float4 w = *reinterpret_cast<const float4*>(cw + h);
        dot += v.x * w.x + v.y * w.y + v.z * w.z + v.w * w.w;
        uint p0 = (uint)f2b(v.x) | ((uint)f2b(v.y) << 16);
        uint p1 = (uint)f2b(v.z) | ((uint)f2b(v.w) << 16);
        *reinterpret_cast<uint*>(&lds[r][h])     = p0;
        *reinterpret_cast<uint*>(&lds[r][h + 2]) = p1;
    }
    dot += __shfl_xor(dot, 1);
    dot += __shfl_xor(dot, 2);
    if (qd == 0) cdot[b * CLEN + c0 + r] = dot;
    __syncthreads();
    // phase2: thread t = h row of ctxT, write 64 c values (128B)
    ushort* dst = ctxT + ((size_t)(b * HID + t)) * CLEN + c0;
    #pragma unroll
    for (int j = 0; j < 8; j++) {
        uint4 w;
        w.x = (uint)lds[j*8+0][t] | ((uint)lds[j*8+1][t] << 16);
        w.y = (uint)lds[j*8+2][t] | ((uint)lds[j*8+3][t] << 16);
        w.z = (uint)lds[j*8+4][t] | ((uint)lds[j*8+5][t] << 16);
        w.w = (uint)lds[j*8+6][t] | ((uint)lds[j*8+7][t] << 16);
        *reinterpret_cast<uint4*>(dst + j * 8) = w;
    }
}

// ============ prep_q: qB[b][q][h] bf16, qT[b][h][q] bf16, qdot ============
// grid 64 (b*2 + qtile64), 256 thr
__global__ __launch_bounds__(256) void prep_q_kernel(
    const float* __restrict__ query, const float* __restrict__ qw,
    ushort* __restrict__ qB, ushort* __restrict__ qT, float* __restrict__ qdot)
{
    __shared__ ushort lds[64][258];
    int bid = blockIdx.x;
    int b = bid >> 1, q0 = (bid & 1) * 64;
    int t = threadIdx.x;
    int r = t >> 2, qd = t & 3;
    const float* src = query + ((size_t)(b * QLEN + q0 + r)) * HID;
    ushort* qBr = qB + ((size_t)(b * QLEN + q0 + r)) * HID;
    float dot = 0.f;
    #pragma unroll
    for (int j = 0; j < 16; j++) {
        int h = j * 16 + qd * 4;
        float4 v = *reinterpret_cast<const float4*>(src + h);
        float4 w = *reinterpret_cast<const float4*>(qw + h);
        dot += v.x * w.x + v.y * w.y + v.z * w.z + v.w * w.w;
        uint p0 = (uint)f2b(v.x) | ((uint)f2b(v.y) << 16);
        uint p1 = (uint)f2b(v.z) | ((uint)f2b(v.w) << 16);
        *reinterpret_cast<uint*>(&lds[r][h])     = p0;
        *reinterpret_cast<uint*>(&lds[r][h + 2]) = p1;
        uint2 pk; pk.x = p0; pk.y = p1;
        *reinterpret_cast<uint2*>(qBr + h) = pk;
    }
    dot += __shfl_xor(dot, 1);
    dot += __shfl_xor(dot, 2);
    if (qd == 0) qdot[b * QLEN + q0 + r] = dot;
    __syncthreads();
    ushort* dst = qT + ((size_t)(b * HID + t)) * QLEN + q0;
    #pragma unroll
    for (int j = 0; j < 8; j++) {
        uint4 w;
        w.x = (uint)lds[j*8+0][t] | ((uint)lds[j*8+1][t] << 16);
        w.y = (uint)lds[j*8+2][t] | ((uint)lds[j*8+3][t] << 16);
        w.z = (uint)lds[j*8+4][t] | ((uint)lds[j*8+5][t] << 16);
        w.w = (uint)lds[j*8+6][t] | ((uint)lds[j*8+7][t] << 16);
        *reinterpret_cast<uint4*>(dst + j * 8) = w;
    }
}

// ====== s_kernel: S = mc@q^T + cdot + qdot + bias; write S bf16, P2T bf16 ======
// grid (16 ctile64, 32 b), 256 thr, waves 2x2, wave tile 32c x 64q, K=256
__global__ __launch_bounds__(256) void s_kernel(
    const float* __restrict__ context, const ushort* __restrict__ qB,
    const float* __restrict__ cqw, const float* __restrict__ cdot,
    const float* __restrict__ qdot, const float* __restrict__ bias,
    ushort* __restrict__ S, ushort* __restrict__ P2T)
{
    __shared__ float ldsS[64][132];
    __shared__ float ldsM[64], ldsR[64];
    int ct = blockIdx.x, b = blockIdx.y;
    int c0 = ct * 64;
    int t = threadIdx.x;
    int w = t >> 6, L = t & 63, g = L >> 4, ln = L & 15;
    int wr = w >> 1, wc = w & 1;

    f32x4 acc[2][4];
    #pragma unroll
    for (int mi = 0; mi < 2; mi++)
        #pragma unroll
        for (int ni = 0; ni < 4; ni++) acc[mi][ni] = (f32x4){0.f, 0.f, 0.f, 0.f};

    const float* ctxB = context + ((size_t)(b * CLEN + c0 + wr * 32)) * HID;
    const ushort* qBb = qB + ((size_t)(b * QLEN + wc * 64)) * HID;

    #pragma unroll 2
    for (int kk = 0; kk < 8; kk++) {
        int k = kk * 32 + g * 8;
        float4 w0 = *reinterpret_cast<const float4*>(cqw + k);
        float4 w1 = *reinterpret_cast<const float4*>(cqw + k + 4);
        bf16x8 a[2];
        #pragma unroll
        for (int mi = 0; mi < 2; mi++) {
            const float* p = ctxB + (size_t)(mi * 16 + ln) * HID + k;
            float4 v0 = *reinterpret_cast<const float4*>(p);
            float4 v1 = *reinterpret_cast<const float4*>(p + 4);
            bf16x8 av;
            av[0] = (short)f2b(v0.x * w0.x); av[1] = (short)f2b(v0.y * w0.y);
            av[2] = (short)f2b(v0.z * w0.z); av[3] = (short)f2b(v0.w * w0.w);
            av[4] = (short)f2b(v1.x * w1.x); av[5] = (short)f2b(v1.y * w1.y);
            av[6] = (short)f2b(v1.z * w1.z); av[7] = (short)f2b(v1.w * w1.w);
            a[mi] = av;
        }
        bf16x8 bq[4];
        #pragma unroll
        for (int ni = 0; ni < 4; ni++)
            bq[ni] = *reinterpret_cast<const bf16x8*>(qBb + (size_t)(ni * 16 + ln) * HID + k);
        #pragma unroll
        for (int mi = 0; mi < 2; mi++)
            #pragma unroll
            for (int ni = 0; ni < 4; ni++)
                acc[mi][ni] = MFMA(a[mi], bq[ni], acc[mi][ni]);
    }

    float bv = bias[0];
    float qdv[4];
    #pragma unroll
    for (int ni = 0; ni < 4; ni++) qdv[ni] = qdot[b * QLEN + wc * 64 + ni * 16 + ln];
    #pragma unroll
    for (int mi = 0; mi < 2; mi++)
        #pragma unroll
        for (int r = 0; r < 4; r++) {
            int row = wr * 32 + mi * 16 + g * 4 + r;
            float cd = cdot[b * CLEN + c0 + row] + bv;
            #pragma unroll
            for (int ni = 0; ni < 4; ni++)
                ldsS[row][wc * 64 + ni * 16 + ln] = acc[mi][ni][r] + cd + qdv[ni];
        }
    __syncthreads();
    // row (axis=2) softmax stats: 4 threads per row, 32 q each
    {
        int row = t >> 2, qs = (t & 3) * 32;
        float4 vr[8];
        float m = -1e30f;
        #pragma unroll
        for (int j = 0; j < 8; j++) {
            vr[j] = *reinterpret_cast<const float4*>(&ldsS[row][qs + j * 4]);
            m = fmaxf(m, fmaxf(fmaxf(vr[j].x, vr[j].y), fmaxf(vr[j].z, vr[j].w)));
        }
        m = fmaxf(m, __shfl_xor(m, 1));
        m = fmaxf(m, __shfl_xor(m, 2));
        float s = 0.f;
        #pragma unroll
        for (int j = 0; j < 8; j++)
            s += __expf(vr[j].x - m) + __expf(vr[j].y - m) +
                 __expf(vr[j].z - m) + __expf(vr[j].w - m);
        s += __shfl_xor(s, 1);
        s += __shfl_xor(s, 2);
        if ((t & 3) == 0) { ldsM[row] = m; ldsR[row] = 1.0f / s; }
    }
    __syncthreads();
    // write S bf16 (coalesced 8B/thread)
    {
        const size_t Sbase = ((size_t)b * CLEN + c0) * QLEN;
        #pragma unroll
        for (int i = 0; i < 8; i++) {
            int flat = t + 256 * i;
            int q4 = flat & 31, c = flat >> 5;
            float4 v = *reinterpret_cast<const float4*>(&ldsS[c][q4 * 4]);
            uint2 pk;
            pk.x = (uint)f2b(v.x) | ((uint)f2b(v.y) << 16);
            pk.y = (uint)f2b(v.z) | ((uint)f2b(v.w) << 16);
            *reinterpret_cast<uint2*>(&S[Sbase + (size_t)c * QLEN + q4 * 4]) = pk;
        }
    }
    // write P2T bf16: P2T[q][c] = exp(S-rowmax)/rowsum
    {
        int q = t >> 1, half = t & 1;
        ushort* dst = P2T + ((size_t)b * QLEN + q) * CLEN + c0 + half * 32;
        #pragma unroll
        for (int jo = 0; jo < 4; jo++) {
            uint pk[4];
            #pragma unroll
            for (int l = 0; l < 4; l++) {
                int c0l = half * 32 + jo * 8 + l * 2;
                float p0 = __expf(ldsS[c0l][q]     - ldsM[c0l])     * ldsR[c0l];
                float p1 = __expf(ldsS[c0l + 1][q] - ldsM[c0l + 1]) * ldsR[c0l + 1];
                pk[l] = (uint)f2b(p0) | ((uint)f2b(p1) << 16);
            }
            uint4 wv; wv.x = pk[0]; wv.y = pk[1]; wv.z = pk[2]; wv.w = pk[3];
            *reinterpret_cast<uint4*>(dst + jo * 8) = wv;
        }
    }
}

// ================= column (axis=1) softmax stats =================
__global__ __launch_bounds__(256) void colstats1_kernel(
    const ushort* __restrict__ S, float* __restrict__ pmax, float* __restrict__ psum)
{
    int b = blockIdx.x, chunk = blockIdx.y;
    int t = threadIdx.x;
    int q = t & 127, half = t >> 7;
    const ushort* Sb = S + ((size_t)b * CLEN + chunk * 128) * QLEN;
    float m = -1e30f, s = 0.f;
    for (int k = 0; k < 64; k++) {
        int c = half + 2 * k;
        float v = b2f(Sb[(size_t)c * QLEN + q]);
        float nm = fmaxf(m, v);
        s = s * __expf(m - nm) + __expf(v - nm);
        m = nm;
    }
    __shared__ float sm[256], ss[256];
    sm[t] = m; ss[t] = s;
    __syncthreads();
    if (t < 128) {
        float m2 = sm[t + 128], s2 = ss[t + 128];
        float M = fmaxf(m, m2);
        float Sv = s * __expf(m - M) + s2 * __expf(m2 - M);
        pmax[((size_t)b * 8 + chunk) * QLEN + q] = M;
        psum[((size_t)b * 8 + chunk) * QLEN + q] = Sv;
    }
}

__global__ __launch_bounds__(256) void colstats2_kernel(
    const float* __restrict__ pmax, const float* __restrict__ psum,
    float* __restrict__ colmax, float* __restrict__ colsumr)
{
    int gid = blockIdx.x * 256 + threadIdx.x;   // b*128+q
    int b = gid >> 7, q = gid & 127;
    float m = -1e30f, s = 0.f;
    #pragma unroll
    for (int ch = 0; ch < 8; ch++) {
        float m2 = pmax[((size_t)b * 8 + ch) * QLEN + q];
        float s2 = psum[((size_t)b * 8 + ch) * QLEN + q];
        float M = fmaxf(m, m2);
        s = s * __expf(m - M) + s2 * __expf(m2 - M);
        m = M;
    }
    colmax[gid] = m;
    colsumr[gid] = 1.0f / s;
}

// ====== t_kernel: Tt[h][q] = sum_c ctxT[h][c] * P2T[q][c]  (MFMA, K-split 4) ======
// grid (16 = ht*4+ks, 32 b), 256 thr, waves 2x2, wave 32h x 64q, K=256/block
__global__ __launch_bounds__(256) void t_kernel(
    const ushort* __restrict__ ctxT, const ushort* __restrict__ P2T,
    float* __restrict__ Tpart)
{
    int x = blockIdx.x, b = blockIdx.y;
    int h0 = (x >> 2) * 64, ks = x & 3;
    int t = threadIdx.x;
    int w = t >> 6, L = t & 63, g = L >> 4, ln = L & 15;
    int wr = w >> 1, wc = w & 1;

    f32x4 acc[2][4];
    #pragma unroll
    for (int mi = 0; mi < 2; mi++)
        #pragma unroll
        for (int ni = 0; ni < 4; ni++) acc[mi][ni] = (f32x4){0.f, 0.f, 0.f, 0.f};

    const ushort* aB = ctxT + ((size_t)(b * HID + h0 + wr * 32)) * CLEN + ks * 256;
    const ushort* bB = P2T + ((size_t)(b * QLEN + wc * 64)) * CLEN + ks * 256;

    #pragma unroll 2
    for (int kk = 0; kk < 8; kk++) {
        int k = kk * 32 + g * 8;
        bf16x8 a[2], bq[4];
        #pragma unroll
        for (int mi = 0; mi < 2; mi++)
            a[mi] = *reinterpret_cast<const bf16x8*>(aB + (size_t)(mi * 16 + ln) * CLEN + k);
        #pragma unroll
        for (int ni = 0; ni < 4; ni++)
            bq[ni] = *reinterpret_cast<const bf16x8*>(bB + (size_t)(ni * 16 + ln) * CLEN + k);
        #pragma unroll
        for (int mi = 0; mi < 2; mi++)
            #pragma unroll
            for (int ni = 0; ni < 4; ni++)
                acc[mi][ni] = MFMA(a[mi], bq[ni], acc[mi][ni]);
    }
    float* dst = Tpart + (size_t)ks * (BATCH * HID * QLEN);
    #pragma unroll
    for (int mi = 0; mi < 2; mi++)
        #pragma unroll
        for (int ni = 0; ni < 4; ni++)
            #pragma unroll
            for (int r = 0; r < 4; r++) {
                int h = h0 + wr * 32 + mi * 16 + g * 4 + r;
                int q = wc * 64 + ni * 16 + ln;
                dst[((size_t)b * HID + h) * QLEN + q] = acc[mi][ni][r];
            }
}

__global__ __launch_bounds__(256) void t_reduce_kernel(
    const float* __restrict__ Tpart, ushort* __restrict__ Tt)
{
    int gid = blockIdx.x * 256 + threadIdx.x;  // float4 index, 262144 total
    const float4* p = reinterpret_cast<const float4*>(Tpart);
    float4 a = p[gid];
    float4 b = p[gid + 262144];
    float4 c = p[gid + 524288];
    float4 d = p[gid + 786432];
    float4 r = make_float4(a.x + b.x + c.x + d.x, a.y + b.y + c.y + d.y,
                           a.z + b.z + c.z + d.z, a.w + b.w + c.w + d.w);
    uint2 pk;
    pk.x = (uint)f2b(r.x) | ((uint)f2b(r.y) << 16);
    pk.y = (uint)f2b(r.z) | ((uint)f2b(r.w) << 16);
    *reinterpret_cast<uint2*>(Tt + (size_t)gid * 4) = pk;
}

// ====== ab_out: A = S@query, B = P1@T, fused concat epilogue ======
// grid (32 = ct*4+ht, 32 b), 256 thr, waves 2x2, wave 64c x 32h, K=128
__global__ __launch_bounds__(256) void ab_out_kernel(
    const ushort* __restrict__ S, const ushort* __restrict__ qT,
    const ushort* __restrict__ Tt, const float* __restrict__ context,
    const float* __restrict__ colmax, const float* __restrict__ colsumr,
    float* __restrict__ out)
{
    __shared__ float ldsT[128][68];
    int x = blockIdx.x, b = blockIdx.y;
    int c0 = (x >> 2) * 128, h0 = (x & 3) * 64;
    int t = threadIdx.x;
    int w = t >> 6, L = t & 63, g = L >> 4, ln = L & 15;
    int wr = w >> 1, wc = w & 1;

    f32x4 accA[4][2], accB[4][2];
    #pragma unroll
    for (int mi = 0; mi < 4; mi++)
        #pragma unroll
        for (int ni = 0; ni < 2; ni++) {
            accA[mi][ni] = (f32x4){0.f, 0.f, 0.f, 0.f};
            accB[mi][ni] = (f32x4){0.f, 0.f, 0.f, 0.f};
        }

    const ushort* Srow = S + ((size_t)(b * CLEN + c0 + wr * 64)) * QLEN;
    const ushort* qTb  = qT + ((size_t)(b * HID + h0 + wc * 32)) * QLEN;
    const ushort* TtB  = Tt + ((size_t)(b * HID + h0 + wc * 32)) * QLEN;
    const float* cmB = colmax + b * QLEN;
    const float* crB = colsumr + b * QLEN;

    #pragma unroll
    for (int kk = 0; kk < 4; kk++) {
        int k = kk * 32 + g * 8;
        float4 cm0 = *reinterpret_cast<const float4*>(cmB + k);
        float4 cm1 = *reinterpret_cast<const float4*>(cmB + k + 4);
        float4 cr0 = *reinterpret_cast<const float4*>(crB + k);
        float4 cr1 = *reinterpret_cast<const float4*>(crB + k + 4);
        float cmv[8] = {cm0.x, cm0.y, cm0.z, cm0.w, cm1.x, cm1.y, cm1.z, cm1.w};
        float crv[8] = {cr0.x, cr0.y, cr0.z, cr0.w, cr1.x, cr1.y, cr1.z, cr1.w};
        bf16x8 sa[4], pa[4];
        #pragma unroll
        for (int mi = 0; mi < 4; mi++) {
            sa[mi] = *reinterpret_cast<const bf16x8*>(Srow + (size_t)(mi * 16 + ln) * QLEN + k);
            bf16x8 pv;
            #pragma unroll
            for (int i = 0; i < 8; i++) {
                float f = b2f((ushort)sa[mi][i]);
                pv[i] = (short)f2b(__expf(f - cmv[i]) * crv[i]);
            }
            pa[mi] = pv;
        }
        bf16x8 bq[2], bt[2];
        #pragma unroll
        for (int ni = 0; ni < 2; ni++) {
            bq[ni] = *reinterpret_cast<const bf16x8*>(qTb + (size_t)(ni * 16 + ln) * QLEN + k);
            bt[ni] = *reinterpret_cast<const bf16x8*>(TtB + (size_t)(ni * 16 + ln) * QLEN + k);
        }
        #pragma unroll
        for (int mi = 0; mi < 4; mi++)
            #pragma unroll
            for (int ni = 0; ni < 2; ni++) {
                accA[mi][ni] = MFMA(sa[mi], bq[ni], accA[mi][ni]);
                accB[mi][ni] = MFMA(pa[mi], bt[ni], accB[mi][ni]);
            }
    }

    // pass A: LDS transpose + write ctx, A, ctx*A
    #pragma unroll
    for (int mi = 0; mi < 4; mi++)
        #pragma unroll
        for (int ni = 0; ni < 2; ni++)
            #pragma unroll
            for (int r = 0; r < 4; r++)
                ldsT[wr * 64 + mi * 16 + g * 4 + r][wc * 32 + ni * 16 + ln] = accA[mi][ni][r];
    __syncthreads();
    #pragma unroll
    for (int i = 0; i < 8; i++) {
        int flat = t + 256 * i;
        int h4 = flat & 15, c = flat >> 4;
        float4 av = *reinterpret_cast<const float4*>(&ldsT[c][h4 * 4]);
        float4 cv = *reinterpret_cast<const float4*>(
            context + ((size_t)(b * CLEN + c0 + c)) * HID + h0 + h4 * 4);
        size_t o = ((size_t)(b * CLEN + c0 + c)) * 1024 + h0 + h4 * 4;
        *reinterpret_cast<float4*>(&out[o]) = cv;
        *reinterpret_cast<float4*>(&out[o + 256]) = av;
        *reinterpret_cast<float4*>(&out[o + 512]) =
            make_float4(cv.x * av.x, cv.y * av.y, cv.z * av.z, cv.w * av.w);
    }
    __syncthreads();
    // pass B: LDS transpose + write ctx*B
    #pragma unroll
    for (int mi = 0; mi < 4; mi++)
        #pragma unroll
        for (int ni = 0; ni < 2; ni++)
            #pragma unroll
            for (int r = 0; r < 4; r++)
                ldsT[wr * 64 + mi * 16 + g * 4 + r][wc * 32 + ni * 16 + ln] = accB[mi][ni][r];
    __syncthreads();
    #pragma unroll
    for (int i = 0; i < 8; i++) {
        int flat = t + 256 * i;
        int h4 = flat & 15, c = flat >> 4;
        float4 bvv = *reinterpret_cast<const float4*>(&ldsT[c][h4 * 4]);
        float4 cv = *reinterpret_cast<const float4*>(
            context + ((size_t)(b * CLEN + c0 + c)) * HID + h0 + h4 * 4);
        size_t o = ((size_t)(b * CLEN + c0 + c)) * 1024 + h0 + h4 * 4;
        *reinterpret_cast<float4*>(&out[o + 768]) =
            make_float4(cv.x * bvv.x, cv.y * bvv.y, cv.z * bvv.z, cv.w * bvv.w);
    }
}

extern "C" void kernel_launch(void* const* d_in, const int* in_sizes, int n_in,
                              void* d_out, int out_size, void* d_ws, size_t ws_size,
                              hipStream_t stream)
{
    (void)in_sizes; (void)n_in; (void)out_size; (void)ws_size;
    const float* context   = (const float*)d_in[0];
    const float* query     = (const float*)d_in[1];
    const float* c_weight  = (const float*)d_in[4];
    const float* q_weight  = (const float*)d_in[5];
    const float* cq_weight = (const float*)d_in[6];
    const float* bias      = (const float*)d_in[7];
    float* out = (float*)d_out;
    float* wsf = (float*)d_ws;

    ushort* ctxT = (ushort*)(wsf);                    // 8,388,608 bf16
    ushort* qB   = (ushort*)(wsf + 4194304);          // 1,048,576
    ushort* qT   = (ushort*)(wsf + 4718592);          // 1,048,576
    ushort* S    = (ushort*)(wsf + 5242880);          // 4,194,304
    ushort* P2T  = (ushort*)(wsf + 7340032);          // 4,194,304
    ushort* Tt   = (ushort*)(wsf + 9437184);          // 1,048,576
    float* Tpart   = wsf + 9961472;                   // 4,194,304 f32
    float* cdot    = wsf + 14155776;                  // 32768
    float* qdot    = cdot + 32768;                    // 4096
    float* pmax    = qdot + 4096;                     // 32768
    float* psum    = pmax + 32768;                    // 32768
    float* colmax  = psum + 32768;                    // 4096
    float* colsumr = colmax + 4096;                   // 4096

    prep_ctx_kernel<<<512, 256, 0, stream>>>(context, c_weight, ctxT, cdot);
    prep_q_kernel<<<64, 256, 0, stream>>>(query, q_weight, qB, qT, qdot);
    s_kernel<<<dim3(16, 32), 256, 0, stream>>>(context, qB, cq_weight, cdot, qdot,
                                               bias, S, P2T);
    colstats1_kernel<<<dim3(32, 8), 256, 0, stream>>>(S, pmax, psum);
    colstats2_kernel<<<16, 256, 0, stream>>>(pmax, psum, colmax, colsumr);
    t_kernel<<<dim3(16, 32), 256, 0, stream>>>(ctxT, P2T, Tpart);
    t_reduce_kernel<<<1024, 256, 0, stream>>>(Tpart, Tt);
    ab_out_kernel<<<dim3(32, 32), 256, 0, stream>>>(S, qT, Tt, context,
                                                    colmax, colsumr, out);
}

// Round 3
// 111.828 us; speedup vs baseline: 1.8688x; 1.0647x over previous
//
#include <hip/hip_runtime.h>
#include <cstdint>
#include <cstddef>

#define BATCH 32
#define CLEN  1024
#define QLEN  128
#define HID   256

typedef __attribute__((ext_vector_type(8))) short bf16x8;
typedef __attribute__((ext_vector_type(4))) float f32x4;

#define MFMA(a, b, c) __builtin_amdgcn_mfma_f32_16x16x32_bf16((a), (b), (c), 0, 0, 0)

__device__ __forceinline__ ushort f2b(float f) {
    union { float f; uint u; } v; v.f = f;
    uint r = (v.u + 0x7fffu + ((v.u >> 16) & 1u)) >> 16;
    return (ushort)r;
}
__device__ __forceinline__ float b2f(ushort u) {
    union { uint u; float f; } v; v.u = ((uint)u) << 16;
    return v.f;
}

// ================= prep: ctxT bf16[b][h][c], mcB bf16[b][c][h]=ctx*cqw,
//                  qB bf16[b][q][h], qT bf16[b][h][q], cdot, qdot =============
// grid 576: blocks 0..511 ctx tiles (b*16+ct64), 512..575 query tiles
__global__ __launch_bounds__(256) void prep_kernel(
    const float* __restrict__ context, const float* __restrict__ query,
    const float* __restrict__ cw, const float* __restrict__ qw,
    const float* __restrict__ cqw,
    ushort* __restrict__ ctxT, ushort* __restrict__ mcB,
    ushort* __restrict__ qB, ushort* __restrict__ qT,
    float* __restrict__ cdot, float* __restrict__ qdot)
{
    __shared__ ushort lds[64][258];
    int bid = blockIdx.x;
    int t = threadIdx.x;
    int r = t >> 2, qd = t & 3;
    if (bid < 512) {
        int b = bid >> 4, c0 = (bid & 15) * 64;
        const float* src = context + ((size_t)(b * CLEN + c0 + r)) * HID;
        ushort* mcr = mcB + ((size_t)(b * CLEN + c0 + r)) * HID;
        float dot = 0.f;
        #pragma unroll
        for (int j = 0; j < 16; j++) {
            int h = j * 16 + qd * 4;
            float4 v  = *reinterpret_cast<const float4*>(src + h);
            float4 w  = *reinterpret_cast<const float4*>(cw + h);
            float4 wc = *reinterpret_cast<const float4*>(cqw + h);
            dot += v.x * w.x + v.y * w.y + v.z * w.z + v.w * w.w;
            uint p0 = (uint)f2b(v.x) | ((uint)f2b(v.y) << 16);
            uint p1 = (uint)f2b(v.z) | ((uint)f2b(v.w) << 16);
            *reinterpret_cast<uint*>(&lds[r][h])     = p0;
            *reinterpret_cast<uint*>(&lds[r][h + 2]) = p1;
            uint2 mc;
            mc.x = (uint)f2b(v.x * wc.x) | ((uint)f2b(v.y * wc.y) << 16);
            mc.y = (uint)f2b(v.z * wc.z) | ((uint)f2b(v.w * wc.w) << 16);
            *reinterpret_cast<uint2*>(mcr + h) = mc;
        }
        dot += __shfl_xor(dot, 1);
        dot += __shfl_xor(dot, 2);
        if (qd == 0) cdot[b * CLEN + c0 + r] = dot;
        __syncthreads();
        ushort* dst = ctxT + ((size_t)(b * HID + t)) * CLEN + c0;
        #pragma unroll
        for (int j = 0; j < 8; j++) {
            uint4 w;
            w.x = (uint)lds[j*8+0][t] | ((uint)lds[j*8+1][t] << 16);
            w.y = (uint)lds[j*8+2][t] | ((uint)lds[j*8+3][t] << 16);
            w.z = (uint)lds[j*8+4][t] | ((uint)lds[j*8+5][t] << 16);
            w.w = (uint)lds[j*8+6][t] | ((uint)lds[j*8+7][t] << 16);
            *reinterpret_cast<uint4*>(dst + j * 8) = w;
        }
    } else {
        int bb = bid - 512;
        int b = bb >> 1, q0 = (bb & 1) * 64;
        const float* src = query + ((size_t)(b * QLEN + q0 + r)) * HID;
        ushort* qBr = qB + ((size_t)(b * QLEN + q0 + r)) * HID;
        float dot = 0.f;
        #pragma unroll
        for (int j = 0; j < 16; j++) {
            int h = j * 16 + qd * 4;
            float4 v = *reinterpret_cast<const float4*>(src + h);
            float4 w = *reinterpret_cast<const float4*>(qw + h);
            dot += v.x * w.x + v.y * w.y + v.z * w.z + v.w * w.w;
            uint p0 = (uint)f2b(v.x) | ((uint)f2b(v.y) << 16);
            uint p1 = (uint)f2b(v.z) | ((uint)f2b(v.w) << 16);
            *reinterpret_cast<uint*>(&lds[r][h])     = p0;
            *reinterpret_cast<uint*>(&lds[r][h + 2]) = p1;
            uint2 pk; pk.x = p0; pk.y = p1;
            *reinterpret_cast<uint2*>(qBr + h) = pk;
        }
        dot += __shfl_xor(dot, 1);
        dot += __shfl_xor(dot, 2);
        if (qd == 0) qdot[b * QLEN + q0 + r] = dot;
        __syncthreads();
        ushort* dst = qT + ((size_t)(b * HID + t)) * QLEN + q0;
        #pragma unroll
        for (int j = 0; j < 8; j++) {
            uint4 w;
            w.x = (uint)lds[j*8+0][t] | ((uint)lds[j*8+1][t] << 16);
            w.y = (uint)lds[j*8+2][t] | ((uint)lds[j*8+3][t] << 16);
            w.z = (uint)lds[j*8+4][t] | ((uint)lds[j*8+5][t] << 16);
            w.w = (uint)lds[j*8+6][t] | ((uint)lds[j*8+7][t] << 16);
            *reinterpret_cast<uint4*>(dst + j * 8) = w;
        }
    }
}

// ====== s_kernel: S = mcB@qB^T + cdot + qdot + bias; write S bf16, P2T bf16 ======
// grid (16 ctile64, 32 b), waves 2x2, wave tile 32c x 64q, K=256
__global__ __launch_bounds__(256) void s_kernel(
    const ushort* __restrict__ mcB, const ushort* __restrict__ qB,
    const float* __restrict__ cdot, const float* __restrict__ qdot,
    const float* __restrict__ bias,
    ushort* __restrict__ S, ushort* __restrict__ P2T)
{
    __shared__ float ldsS[64][132];
    __shared__ float ldsM[64], ldsR[64];
    int ct = blockIdx.x, b = blockIdx.y;
    int c0 = ct * 64;
    int t = threadIdx.x;
    int w = t >> 6, L = t & 63, g = L >> 4, ln = L & 15;
    int wr = w >> 1, wc = w & 1;

    f32x4 acc[2][4];
    #pragma unroll
    for (int mi = 0; mi < 2; mi++)
        #pragma unroll
        for (int ni = 0; ni < 4; ni++) acc[mi][ni] = (f32x4){0.f, 0.f, 0.f, 0.f};

    const ushort* aBase = mcB + ((size_t)(b * CLEN + c0 + wr * 32)) * HID;
    const ushort* qBb   = qB + ((size_t)(b * QLEN + wc * 64)) * HID;

    #pragma unroll 2
    for (int kk = 0; kk < 8; kk++) {
        int k = kk * 32 + g * 8;
        bf16x8 a[2], bq[4];
        #pragma unroll
        for (int mi = 0; mi < 2; mi++)
            a[mi] = *reinterpret_cast<const bf16x8*>(aBase + (size_t)(mi * 16 + ln) * HID + k);
        #pragma unroll
        for (int ni = 0; ni < 4; ni++)
            bq[ni] = *reinterpret_cast<const bf16x8*>(qBb + (size_t)(ni * 16 + ln) * HID + k);
        #pragma unroll
        for (int mi = 0; mi < 2; mi++)
            #pragma unroll
            for (int ni = 0; ni < 4; ni++)
                acc[mi][ni] = MFMA(a[mi], bq[ni], acc[mi][ni]);
    }

    float bv = bias[0];
    float qdv[4];
    #pragma unroll
    for (int ni = 0; ni < 4; ni++) qdv[ni] = qdot[b * QLEN + wc * 64 + ni * 16 + ln];
    #pragma unroll
    for (int mi = 0; mi < 2; mi++)
        #pragma unroll
        for (int r = 0; r < 4; r++) {
            int row = wr * 32 + mi * 16 + g * 4 + r;
            float cd = cdot[b * CLEN + c0 + row] + bv;
            #pragma unroll
            for (int ni = 0; ni < 4; ni++)
                ldsS[row][wc * 64 + ni * 16 + ln] = acc[mi][ni][r] + cd + qdv[ni];
        }
    __syncthreads();
    {
        int row = t >> 2, qs = (t & 3) * 32;
        float4 vr[8];
        float m = -1e30f;
        #pragma unroll
        for (int j = 0; j < 8; j++) {
            vr[j] = *reinterpret_cast<const float4*>(&ldsS[row][qs + j * 4]);
            m = fmaxf(m, fmaxf(fmaxf(vr[j].x, vr[j].y), fmaxf(vr[j].z, vr[j].w)));
        }
        m = fmaxf(m, __shfl_xor(m, 1));
        m = fmaxf(m, __shfl_xor(m, 2));
        float s = 0.f;
        #pragma unroll
        for (int j = 0; j < 8; j++)
            s += __expf(vr[j].x - m) + __expf(vr[j].y - m) +
                 __expf(vr[j].z - m) + __expf(vr[j].w - m);
        s += __shfl_xor(s, 1);
        s += __shfl_xor(s, 2);
        if ((t & 3) == 0) { ldsM[row] = m; ldsR[row] = 1.0f / s; }
    }
    __syncthreads();
    {
        const size_t Sbase = ((size_t)b * CLEN + c0) * QLEN;
        #pragma unroll
        for (int i = 0; i < 8; i++) {
            int flat = t + 256 * i;
            int q4 = flat & 31, c = flat >> 5;
            float4 v = *reinterpret_cast<const float4*>(&ldsS[c][q4 * 4]);
            uint2 pk;
            pk.x = (uint)f2b(v.x) | ((uint)f2b(v.y) << 16);
            pk.y = (uint)f2b(v.z) | ((uint)f2b(v.w) << 16);
            *reinterpret_cast<uint2*>(&S[Sbase + (size_t)c * QLEN + q4 * 4]) = pk;
        }
    }
    {
        int q = t >> 1, half = t & 1;
        ushort* dst = P2T + ((size_t)b * QLEN + q) * CLEN + c0 + half * 32;
        #pragma unroll
        for (int jo = 0; jo < 4; jo++) {
            uint pk[4];
            #pragma unroll
            for (int l = 0; l < 4; l++) {
                int c0l = half * 32 + jo * 8 + l * 2;
                float p0 = __expf(ldsS[c0l][q]     - ldsM[c0l])     * ldsR[c0l];
                float p1 = __expf(ldsS[c0l + 1][q] - ldsM[c0l + 1]) * ldsR[c0l + 1];
                pk[l] = (uint)f2b(p0) | ((uint)f2b(p1) << 16);
            }
            uint4 wv; wv.x = pk[0]; wv.y = pk[1]; wv.z = pk[2]; wv.w = pk[3];
            *reinterpret_cast<uint4*>(dst + jo * 8) = wv;
        }
    }
}

// ====== colstats: per (b, q) max & sum of exp over c (axis=1), one kernel ======
// grid (4 qchunk32, 32 b), block 256 = 32q x 8 csplit
__global__ __launch_bounds__(256) void colstats_kernel(
    const ushort* __restrict__ S, float* __restrict__ colmax, float* __restrict__ colsumr)
{
    __shared__ float red[8][32];
    __shared__ float Mv[32];
    int q0 = blockIdx.x * 32, b = blockIdx.y;
    int t = threadIdx.x, q = t & 31, cs = t >> 5;
    const ushort* p = S + (size_t)b * CLEN * QLEN + (size_t)cs * 128 * QLEN + q0 + q;
    float m0 = -1e30f, m1 = -1e30f, m2 = -1e30f, m3 = -1e30f;
    #pragma unroll 8
    for (int i = 0; i < 128; i += 4) {
        m0 = fmaxf(m0, b2f(p[(size_t)(i + 0) * QLEN]));
        m1 = fmaxf(m1, b2f(p[(size_t)(i + 1) * QLEN]));
        m2 = fmaxf(m2, b2f(p[(size_t)(i + 2) * QLEN]));
        m3 = fmaxf(m3, b2f(p[(size_t)(i + 3) * QLEN]));
    }
    red[cs][q] = fmaxf(fmaxf(m0, m1), fmaxf(m2, m3));
    __syncthreads();
    if (t < 32) {
        float mm = red[0][t];
        #pragma unroll
        for (int j = 1; j < 8; j++) mm = fmaxf(mm, red[j][t]);
        Mv[t] = mm;
    }
    __syncthreads();
    float M = Mv[q];
    float s0 = 0.f, s1 = 0.f, s2 = 0.f, s3 = 0.f;
    #pragma unroll 8
    for (int i = 0; i < 128; i += 4) {
        s0 += __expf(b2f(p[(size_t)(i + 0) * QLEN]) - M);
        s1 += __expf(b2f(p[(size_t)(i + 1) * QLEN]) - M);
        s2 += __expf(b2f(p[(size_t)(i + 2) * QLEN]) - M);
        s3 += __expf(b2f(p[(size_t)(i + 3) * QLEN]) - M);
    }
    __syncthreads();
    red[cs][q] = (s0 + s1) + (s2 + s3);
    __syncthreads();
    if (t < 32) {
        float ss = 0.f;
        #pragma unroll
        for (int j = 0; j < 8; j++) ss += red[j][t];
        colmax[b * QLEN + q0 + t]  = Mv[t];
        colsumr[b * QLEN + q0 + t] = 1.0f / ss;
    }
}

// ====== t_kernel: Tpart[ks][b][h][q] = sum_{c in half ks} ctxT[h][c]*P2T[q][c] ======
// grid (8 = ht*2+ks, 32 b), waves 2x2, wave 32h x 64q, K=512
__global__ __launch_bounds__(256) void t_kernel(
    const ushort* __restrict__ ctxT, const ushort* __restrict__ P2T,
    float* __restrict__ Tpart)
{
    int x = blockIdx.x, b = blockIdx.y;
    int h0 = (x >> 1) * 64, ks = x & 1;
    int t = threadIdx.x;
    int w = t >> 6, L = t & 63, g = L >> 4, ln = L & 15;
    int wr = w >> 1, wc = w & 1;

    f32x4 acc[2][4];
    #pragma unroll
    for (int mi = 0; mi < 2; mi++)
        #pragma unroll
        for (int ni = 0; ni < 4; ni++) acc[mi][ni] = (f32x4){0.f, 0.f, 0.f, 0.f};

    const ushort* aB = ctxT + ((size_t)(b * HID + h0 + wr * 32)) * CLEN + ks * 512;
    const ushort* bB = P2T + ((size_t)(b * QLEN + wc * 64)) * CLEN + ks * 512;

    #pragma unroll 2
    for (int kk = 0; kk < 16; kk++) {
        int k = kk * 32 + g * 8;
        bf16x8 a[2], bq[4];
        #pragma unroll
        for (int mi = 0; mi < 2; mi++)
            a[mi] = *reinterpret_cast<const bf16x8*>(aB + (size_t)(mi * 16 + ln) * CLEN + k);
        #pragma unroll
        for (int ni = 0; ni < 4; ni++)
            bq[ni] = *reinterpret_cast<const bf16x8*>(bB + (size_t)(ni * 16 + ln) * CLEN + k);
        #pragma unroll
        for (int mi = 0; mi < 2; mi++)
            #pragma unroll
            for (int ni = 0; ni < 4; ni++)
                acc[mi][ni] = MFMA(a[mi], bq[ni], acc[mi][ni]);
    }
    float* dst = Tpart + (size_t)ks * (BATCH * HID * QLEN);
    #pragma unroll
    for (int mi = 0; mi < 2; mi++)
        #pragma unroll
        for (int ni = 0; ni < 4; ni++)
            #pragma unroll
            for (int r = 0; r < 4; r++) {
                int h = h0 + wr * 32 + mi * 16 + g * 4 + r;
                int q = wc * 64 + ni * 16 + ln;
                dst[((size_t)b * HID + h) * QLEN + q] = acc[mi][ni][r];
            }
}

__global__ __launch_bounds__(256) void t_reduce_kernel(
    const float* __restrict__ Tpart, ushort* __restrict__ Tt)
{
    int gid = blockIdx.x * 256 + threadIdx.x;  // float4 index, 262144 total
    const float4* p = reinterpret_cast<const float4*>(Tpart);
    float4 a = p[gid];
    float4 b = p[gid + 262144];
    float4 r = make_float4(a.x + b.x, a.y + b.y, a.z + b.z, a.w + b.w);
    uint2 pk;
    pk.x = (uint)f2b(r.x) | ((uint)f2b(r.y) << 16);
    pk.y = (uint)f2b(r.z) | ((uint)f2b(r.w) << 16);
    *reinterpret_cast<uint2*>(Tt + (size_t)gid * 4) = pk;
}

// ====== ab_out: A = S@query, B = P1@T, fused concat epilogue ======
// grid (32 = ct*4+ht, 32 b), waves 2x2, wave 64c x 32h, K=128
__global__ __launch_bounds__(256) void ab_out_kernel(
    const ushort* __restrict__ S, const ushort* __restrict__ qT,
    const ushort* __restrict__ Tt, const float* __restrict__ context,
    const float* __restrict__ colmax, const float* __restrict__ colsumr,
    float* __restrict__ out)
{
    __shared__ float ldsT[128][68];
    int x = blockIdx.x, b = blockIdx.y;
    int c0 = (x >> 2) * 128, h0 = (x & 3) * 64;
    int t = threadIdx.x;
    int w = t >> 6, L = t & 63, g = L >> 4, ln = L & 15;
    int wr = w >> 1, wc = w & 1;

    f32x4 accA[4][2], accB[4][2];
    #pragma unroll
    for (int mi = 0; mi < 4; mi++)
        #pragma unroll
        for (int ni = 0; ni < 2; ni++) {
            accA[mi][ni] = (f32x4){0.f, 0.f, 0.f, 0.f};
            accB[mi][ni] = (f32x4){0.f, 0.f, 0.f, 0.f};
        }

    const ushort* Srow = S + ((size_t)(b * CLEN + c0 + wr * 64)) * QLEN;
    const ushort* qTb  = qT + ((size_t)(b * HID + h0 + wc * 32)) * QLEN;
    const ushort* TtB  = Tt + ((size_t)(b * HID + h0 + wc * 32)) * QLEN;
    const float* cmB = colmax + b * QLEN;
    const float* crB = colsumr + b * QLEN;

    #pragma unroll
    for (int kk = 0; kk < 4; kk++) {
        int k = kk * 32 + g * 8;
        float4 cm0 = *reinterpret_cast<const float4*>(cmB + k);
        float4 cm1 = *reinterpret_cast<const float4*>(cmB + k + 4);
        float4 cr0 = *reinterpret_cast<const float4*>(crB + k);
        float4 cr1 = *reinterpret_cast<const float4*>(crB + k + 4);
        float cmv[8] = {cm0.x, cm0.y, cm0.z, cm0.w, cm1.x, cm1.y, cm1.z, cm1.w};
        float crv[8] = {cr0.x, cr0.y, cr0.z, cr0.w, cr1.x, cr1.y, cr1.z, cr1.w};
        bf16x8 sa[4], pa[4];
        #pragma unroll
        for (int mi = 0; mi < 4; mi++) {
            sa[mi] = *reinterpret_cast<const bf16x8*>(Srow + (size_t)(mi * 16 + ln) * QLEN + k);
            bf16x8 pv;
            #pragma unroll
            for (int i = 0; i < 8; i++) {
                float f = b2f((ushort)sa[mi][i]);
                pv[i] = (short)f2b(__expf(f - cmv[i]) * crv[i]);
            }
            pa[mi] = pv;
        }
        bf16x8 bq[2], bt[2];
        #pragma unroll
        for (int ni = 0; ni < 2; ni++) {
            bq[ni] = *reinterpret_cast<const bf16x8*>(qTb + (size_t)(ni * 16 + ln) * QLEN + k);
            bt[ni] = *reinterpret_cast<const bf16x8*>(TtB + (size_t)(ni * 16 + ln) * QLEN + k);
        }
        #pragma unroll
        for (int mi = 0; mi < 4; mi++)
            #pragma unroll
            for (int ni = 0; ni < 2; ni++) {
                accA[mi][ni] = MFMA(sa[mi], bq[ni], accA[mi][ni]);
                accB[mi][ni] = MFMA(pa[mi], bt[ni], accB[mi][ni]);
            }
    }

    #pragma unroll
    for (int mi = 0; mi < 4; mi++)
        #pragma unroll
        for (int ni = 0; ni < 2; ni++)
            #pragma unroll
            for (int r = 0; r < 4; r++)
                ldsT[wr * 64 + mi * 16 + g * 4 + r][wc * 32 + ni * 16 + ln] = accA[mi][ni][r];
    __syncthreads();
    #pragma unroll
    for (int i = 0; i < 8; i++) {
        int flat = t + 256 * i;
        int h4 = flat & 15, c = flat >> 4;
        float4 av = *reinterpret_cast<const float4*>(&ldsT[c][h4 * 4]);
        float4 cv = *reinterpret_cast<const float4*>(
            context + ((size_t)(b * CLEN + c0 + c)) * HID + h0 + h4 * 4);
        size_t o = ((size_t)(b * CLEN + c0 + c)) * 1024 + h0 + h4 * 4;
        *reinterpret_cast<float4*>(&out[o]) = cv;
        *reinterpret_cast<float4*>(&out[o + 256]) = av;
        *reinterpret_cast<float4*>(&out[o + 512]) =
            make_float4(cv.x * av.x, cv.y * av.y, cv.z * av.z, cv.w * av.w);
    }
    __syncthreads();
    #pragma unroll
    for (int mi = 0; mi < 4; mi++)
        #pragma unroll
        for (int ni = 0; ni < 2; ni++)
            #pragma unroll
            for (int r = 0; r < 4; r++)
                ldsT[wr * 64 + mi * 16 + g * 4 + r][wc * 32 + ni * 16 + ln] = accB[mi][ni][r];
    __syncthreads();
    #pragma unroll
    for (int i = 0; i < 8; i++) {
        int flat = t + 256 * i;
        int h4 = flat & 15, c = flat >> 4;
        float4 bvv = *reinterpret_cast<const float4*>(&ldsT[c][h4 * 4]);
        float4 cv = *reinterpret_cast<const float4*>(
            context + ((size_t)(b * CLEN + c0 + c)) * HID + h0 + h4 * 4);
        size_t o = ((size_t)(b * CLEN + c0 + c)) * 1024 + h0 + h4 * 4;
        *reinterpret_cast<float4*>(&out[o + 768]) =
            make_float4(cv.x * bvv.x, cv.y * bvv.y, cv.z * bvv.z, cv.w * bvv.w);
    }
}

extern "C" void kernel_launch(void* const* d_in, const int* in_sizes, int n_in,
                              void* d_out, int out_size, void* d_ws, size_t ws_size,
                              hipStream_t stream)
{
    (void)in_sizes; (void)n_in; (void)out_size; (void)ws_size;
    const float* context   = (const float*)d_in[0];
    const float* query     = (const float*)d_in[1];
    const float* c_weight  = (const float*)d_in[4];
    const float* q_weight  = (const float*)d_in[5];
    const float* cq_weight = (const float*)d_in[6];
    const float* bias      = (const float*)d_in[7];
    float* out = (float*)d_out;
    char* wsb  = (char*)d_ws;

    ushort* ctxT = (ushort*)(wsb);                       // 8,388,608 elem
    ushort* mcB  = (ushort*)(wsb + 16777216);            // 8,388,608
    ushort* qB   = (ushort*)(wsb + 33554432);            // 1,048,576
    ushort* qT   = (ushort*)(wsb + 35651584);            // 1,048,576
    ushort* S    = (ushort*)(wsb + 37748736);            // 4,194,304
    ushort* P2T  = (ushort*)(wsb + 46137344);            // 4,194,304
    ushort* Tt   = (ushort*)(wsb + 54525952);            // 1,048,576
    float*  Tpart = (float*)(wsb + 56623104);            // 2,097,152 f32
    float*  cdot  = (float*)(wsb + 65011712);            // 32768
    float*  qdot  = cdot + 32768;                        // 4096
    float*  colmax  = qdot + 4096;                       // 4096
    float*  colsumr = colmax + 4096;                     // 4096

    prep_kernel<<<576, 256, 0, stream>>>(context, query, c_weight, q_weight,
                                         cq_weight, ctxT, mcB, qB, qT, cdot, qdot);
    s_kernel<<<dim3(16, 32), 256, 0, stream>>>(mcB, qB, cdot, qdot, bias, S, P2T);
    colstats_kernel<<<dim3(4, 32), 256, 0, stream>>>(S, colmax, colsumr);
    t_kernel<<<dim3(8, 32), 256, 0, stream>>>(ctxT, P2T, Tpart);
    t_reduce_kernel<<<1024, 256, 0, stream>>>(Tpart, Tt);
    ab_out_kernel<<<dim3(32, 32), 256, 0, stream>>>(S, qT, Tt, context,
                                                    colmax, colsumr, out);
}